// Round 10
// baseline (881.818 us; speedup 1.0000x reference)
//
#include <hip/hip_runtime.h>
#include <hip/hip_bf16.h>
#include <stdint.h>

#define B_ 16
#define S_ 2048
#define H_ 1024
static constexpr float NEG_INF_F = -10000000.0f;
static constexpr float SCALE_F   = 0.03125f;   // 1/sqrt(1024)

#define BM 256
#define BN 256
#define BK 64
#define HALF_BYTES 16384     // 128 rows x 64 cols x 2B
#define OPBUF_BYTES 32768    // one operand, one K-tile (2 halves)

typedef __attribute__((ext_vector_type(4))) float  f32x4;
typedef __attribute__((ext_vector_type(8))) short  bf16x8;
typedef __attribute__((ext_vector_type(4))) short  s16x4;

__device__ __forceinline__ short f2bf(float f) {
  uint32_t u = __float_as_uint(f);
  u = (u + 0x7FFFu + ((u >> 16) & 1u)) >> 16;   // RNE bf16
  return (short)u;
}

__device__ __forceinline__ void gload16(const void* g, void* l) {
  __builtin_amdgcn_global_load_lds(
      (const __attribute__((address_space(1))) unsigned int*)g,
      (__attribute__((address_space(3))) unsigned int*)l, 16, 0, 0);
}

// Swizzled LDS fragment read: operand buffer = two 16KB halves of [128][64] bf16.
// XOR-swizzle (T2): byte ^= (row&7)<<4 — same involution as the staging source.
__device__ __forceinline__ bf16x8 lds_frag(const char* buf, int r, int k) {
  int byte = ((r >> 7) << 14) + ((r & 127) << 7) + (k << 1);
  byte ^= (r & 7) << 4;
  return *(const bf16x8*)(buf + byte);
}

// Stage one 128x64 half-tile: linear LDS dest (gload_lds requirement),
// inverse-swizzled per-lane global source (rule #21). 512 threads x 2 loads.
__device__ __forceinline__ void stage_half(const short* __restrict__ rows0,
                                           int ld, int kt, char* dst) {
  const int t = threadIdx.x, w = t >> 6, l = t & 63;
  #pragma unroll
  for (int j = 0; j < 2; ++j) {
    const int idx16 = j * 512 + w * 64 + l;       // 16B-granule index
    const int r  = idx16 >> 3;                    // row 0..127
    const int cs = ((l & 7) << 4) ^ ((r & 7) << 4);
    gload16(rows0 + (size_t)r * ld + kt + (cs >> 1),
            dst + (size_t)(j * 512 + w * 64) * 16);
  }
}

// 256x256xK bf16 GEMM core, 8 waves (2Mx4N), BK=64, double-buffered 128KB LDS.
// R8-proven schedule: all 8 loads of tile i+1 issued at tile i start; 4 MFMA
// phases (per-phase lgkmcnt(0)+sched_barrier, lockstep barriers); vmcnt(0)+
// barrier at tile end.
// Epilogue (MODES 0/2/3): OPERAND-SWAPPED MFMA — mfma(b,a) transposes the C/D
// fragment so each thread's 4 regs = 4 consecutive COLUMNS of one row ->
// packed s16x4/f32x4 stores (32 instead of 128 per thread).
// MODE 0: +bias, out bf16 row-major (swapped)
// MODE 1: +bias, out bf16 transposed V^T (unswapped; row-packed already)
// MODE 2: out f32 = acc*scale + causal mask, + column partials (swapped)
// MODE 3: out f32, triangular K-loop + last BK tile (swapped)
template<int MODE>
__device__ __forceinline__ void gemm_core256(
    const short* __restrict__ A, const short* __restrict__ Bm,
    const float* __restrict__ bias, void* __restrict__ Cp,
    int K, int lda, int ldb, int ldc, int z, long long strC,
    int row0, int col0, int bx, char* lds, float2* __restrict__ partials) {
  constexpr bool SW = (MODE != 1);        // swapped C/D orientation
  char* ldsA = lds;                       // [2][OPBUF]
  char* ldsB = lds + 2 * OPBUF_BYTES;
  const int lane = threadIdx.x & 63;
  const int wid  = threadIdx.x >> 6;
  const int wm = wid >> 2;                // 0..1  (rows wm*128..+127)
  const int wn = wid & 3;                 // 0..3  (cols wn*64..+63)
  const int lr = lane & 15;
  const int hi4 = (lane >> 4) << 2;
  const int lk = (lane >> 4) << 3;

  int kmain = K;
  if constexpr (MODE == 3) { int km = (bx + 1) * BM; kmain = km < K ? km : K; }
  const int ntm = kmain / BK;
  const int nt  = ntm + ((MODE == 3 && kmain < K) ? 1 : 0);  // + last-BK tile (col 2047)

  f32x4 acc[8][4] = {};

  const short* Arows0 = A + (size_t)row0 * lda;
  const short* Arows1 = Arows0 + (size_t)128 * lda;
  const short* Brows0 = Bm + (size_t)col0 * ldb;
  const short* Brows1 = Brows0 + (size_t)128 * ldb;

  auto stage_tile = [&](int buf, int kt) {          // 8 gload16 per thread
    stage_half(Brows0, ldb, kt, ldsB + buf * OPBUF_BYTES);
    stage_half(Brows1, ldb, kt, ldsB + buf * OPBUF_BYTES + HALF_BYTES);
    stage_half(Arows0, lda, kt, ldsA + buf * OPBUF_BYTES);
    stage_half(Arows1, lda, kt, ldsA + buf * OPBUF_BYTES + HALF_BYTES);
  };

  // prologue: tile 0 fully resident before phase 0
  stage_tile(0, 0);
  asm volatile("s_waitcnt vmcnt(0)" ::: "memory");
  __builtin_amdgcn_s_barrier();

  for (int i = 0; i < nt; ++i) {
    const int c = i & 1;
    const char* bA = ldsA + c * OPBUF_BYTES;
    const char* bB = ldsB + c * OPBUF_BYTES;
    if (i + 1 < nt) {                     // prefetch tile i+1 into c^1 (free now)
      const int ktn = (i + 1 < ntm) ? (i + 1) * BK : K - BK;
      stage_tile(c ^ 1, ktn);
    }

    bf16x8 bfr[4][2];
    #pragma unroll
    for (int q = 0; q < 4; ++q) {         // phase q: output rows q*32..+31
      if (q == 0) {
        #pragma unroll
        for (int nf = 0; nf < 4; ++nf)
          #pragma unroll
          for (int ks = 0; ks < 2; ++ks)
            bfr[nf][ks] = lds_frag(bB, wn * 64 + nf * 16 + lr, ks * 32 + lk);
      }
      bf16x8 af[2][2];
      #pragma unroll
      for (int fm = 0; fm < 2; ++fm)
        #pragma unroll
        for (int ks = 0; ks < 2; ++ks)
          af[fm][ks] = lds_frag(bA, wm * 128 + q * 32 + fm * 16 + lr, ks * 32 + lk);
      asm volatile("s_waitcnt lgkmcnt(0)" ::: "memory");
      __builtin_amdgcn_sched_barrier(0);  // rule #18: pin MFMA after the wait
      __builtin_amdgcn_s_setprio(1);
      #pragma unroll
      for (int fm = 0; fm < 2; ++fm)
        #pragma unroll
        for (int nf = 0; nf < 4; ++nf)
          #pragma unroll
          for (int ks = 0; ks < 2; ++ks) {
            if constexpr (SW)
              acc[q * 2 + fm][nf] = __builtin_amdgcn_mfma_f32_16x16x32_bf16(
                  bfr[nf][ks], af[fm][ks], acc[q * 2 + fm][nf], 0, 0, 0);
            else
              acc[q * 2 + fm][nf] = __builtin_amdgcn_mfma_f32_16x16x32_bf16(
                  af[fm][ks], bfr[nf][ks], acc[q * 2 + fm][nf], 0, 0, 0);
          }
      __builtin_amdgcn_s_setprio(0);
      if (q < 3) __builtin_amdgcn_s_barrier();   // lockstep between phases
    }
    asm volatile("s_waitcnt vmcnt(0)" ::: "memory");
    __builtin_amdgcn_s_barrier();
  }

  // ---- Epilogues ----
  // Swapped C/D layout per frag: value C[m][n], m = frag_m_base + lr,
  //                              n = frag_n_base + hi4 + r   (r = reg 0..3)
  if constexpr (MODE == 0) {
    short* out = (short*)Cp;
    #pragma unroll
    for (int nf = 0; nf < 4; ++nf) {
      const int n0 = col0 + wn * 64 + nf * 16 + hi4;
      const f32x4 b4 = *(const f32x4*)&bias[n0];
      #pragma unroll
      for (int mf = 0; mf < 8; ++mf) {
        const int m = row0 + wm * 128 + mf * 16 + lr;
        f32x4 a = acc[mf][nf];
        s16x4 pk;
        #pragma unroll
        for (int r = 0; r < 4; ++r) pk[r] = f2bf(a[r] + b4[r]);
        *(s16x4*)&out[(size_t)m * ldc + n0] = pk;
      }
    }
  } else if constexpr (MODE == 1) {
    // unswapped: col = lane&15 (n), row = hi4 + reg (m)
    #pragma unroll
    for (int mf = 0; mf < 8; ++mf) {
      #pragma unroll
      for (int nf = 0; nf < 4; ++nf) {
        const int mb = row0 + wm * 128 + mf * 16 + hi4;
        const int n  = col0 + wn * 64 + nf * 16 + lr;
        const float bv = bias[n];
        const int bb = mb >> 11;           // batch (S_=2048)
        const int ss = mb & (S_ - 1);
        f32x4 a = acc[mf][nf];
        s16x4 pk;
        #pragma unroll
        for (int r = 0; r < 4; ++r) pk[r] = f2bf(a[r] + bv);
        *(s16x4*)((short*)Cp + ((size_t)bb * H_ + n) * S_ + ss) = pk;
      }
    }
  } else if constexpr (MODE == 2) {
    float* out = (float*)Cp + (size_t)z * strC;
    f32x4 pmv[4], psv[4];
    #pragma unroll
    for (int nf = 0; nf < 4; ++nf)
      #pragma unroll
      for (int r = 0; r < 4; ++r) { pmv[nf][r] = -3.0e38f; psv[nf][r] = 0.0f; }
    // pass 1: store masked scores + per-thread column max
    #pragma unroll
    for (int nf = 0; nf < 4; ++nf) {
      const int n0 = col0 + wn * 64 + nf * 16 + hi4;
      #pragma unroll
      for (int mf = 0; mf < 8; ++mf) {
        const int m = row0 + wm * 128 + mf * 16 + lr;
        f32x4 a = acc[mf][nf];
        f32x4 v;
        #pragma unroll
        for (int r = 0; r < 4; ++r) {
          v[r] = a[r] * SCALE_F + (n0 + r >= m ? NEG_INF_F : 0.0f);
          pmv[nf][r] = fmaxf(pmv[nf][r], v[r]);
        }
        *(f32x4*)&out[(size_t)m * ldc + n0] = v;
      }
    }
    // pass 2: per-thread column sum of exp
    #pragma unroll
    for (int nf = 0; nf < 4; ++nf) {
      const int n0 = col0 + wn * 64 + nf * 16 + hi4;
      #pragma unroll
      for (int mf = 0; mf < 8; ++mf) {
        const int m = row0 + wm * 128 + mf * 16 + lr;
        f32x4 a = acc[mf][nf];
        #pragma unroll
        for (int r = 0; r < 4; ++r) {
          float v = a[r] * SCALE_F + (n0 + r >= m ? NEG_INF_F : 0.0f);
          psv[nf][r] += __expf(v - pmv[nf][r]);   // masked -> exactly 0
        }
      }
    }
    // reduce over the 16 m-lanes (lr) within each hi-group
    float* smx = (float*)lds;             // LDS free after K-loop (barrier done)
    float* sse = smx + 512;
    #pragma unroll
    for (int nf = 0; nf < 4; ++nf)
      #pragma unroll
      for (int r = 0; r < 4; ++r) {
        float m = pmv[nf][r], s = psv[nf][r];
        #pragma unroll
        for (int d = 1; d < 16; d <<= 1) {
          float om = __shfl_xor(m, d);
          float os = __shfl_xor(s, d);
          float nm = fmaxf(m, om);
          s = s * __expf(m - nm) + os * __expf(om - nm);
          m = nm;
        }
        pmv[nf][r] = m; psv[nf][r] = s;
      }
    if (lr == 0) {
      #pragma unroll
      for (int nf = 0; nf < 4; ++nf)
        #pragma unroll
        for (int r = 0; r < 4; ++r) {
          const int cIB = wn * 64 + nf * 16 + hi4 + r;
          smx[wm * 256 + cIB] = pmv[nf][r];
          sse[wm * 256 + cIB] = psv[nf][r];
        }
    }
    __syncthreads();
    if (threadIdx.x < 256) {
      const int col = threadIdx.x;
      float m0 = smx[col], m1 = smx[256 + col];
      float s0 = sse[col], s1 = sse[256 + col];
      float mm = fmaxf(m0, m1);
      float ss = s0 * __expf(m0 - mm) + s1 * __expf(m1 - mm);
      float2 pv; pv.x = mm; pv.y = ss;
      partials[((size_t)z * 8 + (row0 >> 8)) * S_ + col0 + col] = pv;
    }
  } else {
    float* out = (float*)Cp + (size_t)z * strC;
    #pragma unroll
    for (int nf = 0; nf < 4; ++nf) {
      const int n0 = col0 + wn * 64 + nf * 16 + hi4;
      #pragma unroll
      for (int mf = 0; mf < 8; ++mf) {
        const int m = row0 + wm * 128 + mf * 16 + lr;
        *(f32x4*)&out[(size_t)m * ldc + n0] = acc[mf][nf];
      }
    }
  }
}

struct ProjArgs {
  const short *xq, *xk, *xv, *wq, *wk, *wv;
  const float *bq, *bk, *bv;
  short *oq, *ok, *ov;
};

// All three projections; grid (4, 128, 3) = 1536 blocks, XCD-chunked swizzle.
__launch_bounds__(512, 1)
__global__ void proj3(ProjArgs p) {
  __shared__ char lds[4 * OPBUF_BYTES];
  const int bid = blockIdx.x + (blockIdx.y << 2) + (blockIdx.z << 9);
  const int s = (bid & 7) * 192 + (bid >> 3);       // 1536/8 = 192, bijective
  const int z = s >> 9;
  const int y = (s & 511) >> 2;
  const int x = s & 3;
  const int row0 = y * BM;
  const int col0 = x * BN;
  if (z == 0)
    gemm_core256<0>(p.xq, p.wq, p.bq, p.oq, H_, H_, H_, H_, 0, 0LL, row0, col0, x, lds, nullptr);
  else if (z == 1)
    gemm_core256<0>(p.xk, p.wk, p.bk, p.ok, H_, H_, H_, H_, 0, 0LL, row0, col0, x, lds, nullptr);
  else
    gemm_core256<1>(p.xv, p.wv, p.bv, p.ov, H_, H_, H_, 0, 0, 0LL, row0, col0, x, lds, nullptr);
}

// Scores (+scale, +causal mask, +column partials); triangular tile skip except
// last tile-column. grid (8,8,16) = 1024 blocks, XCD-chunked swizzle.
__launch_bounds__(512, 1)
__global__ void scores_k(const short* __restrict__ Qb, const short* __restrict__ Kb,
                         float* __restrict__ attn, float2* __restrict__ partials) {
  const int bid = blockIdx.x + (blockIdx.y << 3) + (blockIdx.z << 6);
  const int s = (bid & 7) * 128 + (bid >> 3);       // 1024/8 = 128, bijective
  const int bz = s >> 6;
  const int by = (s >> 3) & 7;
  const int bx = s & 7;
  if (by > bx && by != 7) return;
  __shared__ char lds[4 * OPBUF_BYTES];
  const size_t zo = (size_t)bz * S_ * H_;
  gemm_core256<2>(Qb + zo, Kb + zo, nullptr, attn, H_, H_, H_, S_, bz,
                  (long long)S_ * S_, bx * BM, by * BN, bx, lds, partials);
}

// Context = attn_b @ V^T; triangular K-loop (+ last BK tile for column 2047).
// grid (8,4,16) = 512 blocks, XCD-chunked swizzle.
__launch_bounds__(512, 1)
__global__ void ctx_k(const short* __restrict__ attn_b, const short* __restrict__ Vt,
                      float* __restrict__ ctx) {
  const int bid = blockIdx.x + (blockIdx.y << 3) + (blockIdx.z << 5);
  const int s = (bid & 7) * 64 + (bid >> 3);        // 512/8 = 64, bijective
  const int bz = s >> 5;
  const int by = (s >> 3) & 3;
  const int bx = s & 7;
  __shared__ char lds[4 * OPBUF_BYTES];
  gemm_core256<3>(attn_b + (size_t)bz * S_ * S_, Vt + (size_t)bz * H_ * S_,
                  nullptr, ctx, S_, S_, S_, H_, bz, (long long)S_ * H_,
                  bx * BM, by * BN, bx, lds, nullptr);
}

// All six f32->bf16 conversions in one launch. grid (2048, 4).
__launch_bounds__(256)
__global__ void cvt6(const float* __restrict__ q, const float* __restrict__ k,
                     const float* __restrict__ v, const float* __restrict__ wq,
                     const float* __restrict__ wk, const float* __restrict__ wv,
                     short* __restrict__ xq, short* __restrict__ xk,
                     short* __restrict__ xv, short* __restrict__ wqb,
                     short* __restrict__ wkb, short* __restrict__ wvb) {
  const int y = blockIdx.y;
  const int stride = gridDim.x * 256;
  if (y < 3) {
    const float* s = (y == 0) ? q : (y == 1) ? k : v;
    short* d       = (y == 0) ? xq : (y == 1) ? xk : xv;
    const int n4 = (B_ * S_ * H_) / 4;
    for (int i = blockIdx.x * 256 + threadIdx.x; i < n4; i += stride) {
      f32x4 x = ((const f32x4*)s)[i];
      s16x4 o;
      #pragma unroll
      for (int j = 0; j < 4; ++j) o[j] = f2bf(x[j]);
      ((s16x4*)d)[i] = o;
    }
  } else {
    const int w4 = (H_ * H_) / 4;          // 2^18
    for (int i = blockIdx.x * 256 + threadIdx.x; i < 3 * w4; i += stride) {
      const int wsel = i >> 18;
      const int j = i & (w4 - 1);
      const float* s = (wsel == 0) ? wq : (wsel == 1) ? wk : wv;
      short* d       = (wsel == 0) ? wqb : (wsel == 1) ? wkb : wvb;
      f32x4 x = ((const f32x4*)s)[j];
      s16x4 o;
      #pragma unroll
      for (int jj = 0; jj < 4; ++jj) o[jj] = f2bf(x[jj]);
      ((s16x4*)d)[j] = o;
    }
  }
}

// Column softmax normalize pass: combine per-tile partials (no raw re-read),
// then a single read+write pass producing f32 attn + bf16 copy.
__launch_bounds__(256)
__global__ void softmax_col(float* __restrict__ attn, short* __restrict__ attn_b,
                            const float2* __restrict__ partials) {
  const int b  = blockIdx.y;
  const int t  = threadIdx.x;
  const int cg = t & 7;
  const int qo = t >> 3;                  // 0..31
  const int k0 = blockIdx.x * 32 + cg * 4;
  float* base = attn + (size_t)b * S_ * S_;
  short* bb   = attn_b + (size_t)b * S_ * S_;
  const bool full = (k0 == S_ - 4);       // group holding the all-masked col S-1

  __shared__ f32x4 bM[8], bI[8];
  if (qo == 0) {
    const int by = k0 >> 8;
    const int bxlo = (by == 7) ? 0 : by;  // tiles scores_k actually computed
    f32x4 M4, Sm;
    #pragma unroll
    for (int i = 0; i < 4; ++i) { M4[i] = -3.0e38f; Sm[i] = 0.0f; }
    for (int bx = bxlo; bx < 8; ++bx) {
      const float2* p = partials + ((size_t)b * 8 + bx) * S_ + k0;
      #pragma unroll
      for (int i = 0; i < 4; ++i) {
        float2 pv = p[i];
        float nm = fmaxf(M4[i], pv.x);
        Sm[i] = Sm[i] * __expf(M4[i] - nm) + pv.y * __expf(pv.x - nm);
        M4[i] = nm;
      }
    }
    f32x4 inv;
    #pragma unroll
    for (int i = 0; i < 4; ++i) inv[i] = 1.0f / Sm[i];
    bM[cg] = M4;
    bI[cg] = inv;
  }
  __syncthreads();
  const f32x4 M4  = bM[cg];
  const f32x4 inv = bI[cg];

  for (int q = qo; q < S_; q += 32) {
    const size_t off = (size_t)q * S_ + k0;
    if (full || q > k0) {
      f32x4 x = *(const f32x4*)&base[off];
      f32x4 r;
      s16x4 rb;
      #pragma unroll
      for (int i = 0; i < 4; ++i) { r[i] = __expf(x[i] - M4[i]) * inv[i]; rb[i] = f2bf(r[i]); }
      *(f32x4*)&base[off] = r;
      *(s16x4*)&bb[off]   = rb;
    } else {
      f32x4 zr;
      s16x4 zb;
      #pragma unroll
      for (int i = 0; i < 4; ++i) { zr[i] = 0.0f; zb[i] = 0; }
      *(f32x4*)&base[off] = zr;
      *(s16x4*)&bb[off]   = zb;
    }
  }
}

extern "C" void kernel_launch(void* const* d_in, const int* in_sizes, int n_in,
                              void* d_out, int out_size, void* d_ws, size_t ws_size,
                              hipStream_t stream) {
  const float* queries = (const float*)d_in[0];
  const float* keys    = (const float*)d_in[1];
  const float* values  = (const float*)d_in[2];
  const float* Wq = (const float*)d_in[3];
  const float* bq = (const float*)d_in[4];
  const float* Wk = (const float*)d_in[5];
  const float* bk = (const float*)d_in[6];
  const float* Wv = (const float*)d_in[7];
  const float* bv = (const float*)d_in[8];

  float* ctx  = (float*)d_out;                       // (B,S,H) f32
  float* attn = ctx + (size_t)B_ * S_ * H_;          // (B,S,S) f32

  short* Qb = (short*)d_ws;                          // (B,S,H) bf16
  short* Kb = Qb + (size_t)B_ * S_ * H_;
  short* Vt = Kb + (size_t)B_ * S_ * H_;             // (B,H,S) bf16
  short* attn_b = Qb;                                // (B,S,S) bf16 == Qb+Kb exactly

  // bf16 weight scratch + softmax partials inside ctx region (written last):
  short* Wqb = (short*)ctx;                          // 3x (H,H) bf16 = 6 MB
  short* Wkb = Wqb + (size_t)H_ * H_;
  short* Wvb = Wkb + (size_t)H_ * H_;
  float2* partials = (float2*)(Wvb + (size_t)H_ * H_);  // (B,8,S) float2 = 2 MB
  short* Xq = (short*)attn;                          // 3x (B,S,H) bf16 in attn region
  short* Xk = Xq + (size_t)B_ * S_ * H_;
  short* Xv = Xk + (size_t)B_ * S_ * H_;

  // 0) all f32->bf16 conversions, one launch
  cvt6<<<dim3(2048, 4, 1), dim3(256, 1, 1), 0, stream>>>(queries, keys, values,
                                                         Wq, Wk, Wv,
                                                         Xq, Xk, Xv, Wqb, Wkb, Wvb);

  // 1) All projections, one launch: M = 32768, N = H, K = H
  ProjArgs pa{Xq, Xk, Xv, Wqb, Wkb, Wvb, bq, bk, bv, Qb, Kb, Vt};
  proj3<<<dim3(H_ / BN, 32768 / BM, 3), dim3(512, 1, 1), 0, stream>>>(pa);

  // 2) Scores (+scale, +causal mask, +partials) -> attn region
  scores_k<<<dim3(S_ / BM, S_ / BN, B_), dim3(512, 1, 1), 0, stream>>>(Qb, Kb, attn, partials);

  // 3) Column softmax normalize (partials-based, single pass) + bf16 copy
  softmax_col<<<dim3(S_ / 32, B_, 1), dim3(256, 1, 1), 0, stream>>>(attn, attn_b, partials);

  // 4) context = attn_b @ V^T (all bf16, triangular K-loop + last BK tile)
  ctx_k<<<dim3(S_ / BM, H_ / BN, B_), dim3(512, 1, 1), 0, stream>>>(attn_b, Vt, ctx);
}

// Round 11
// 805.505 us; speedup vs baseline: 1.0947x; 1.0947x over previous
//
#include <hip/hip_runtime.h>
#include <hip/hip_bf16.h>
#include <stdint.h>

#define B_ 16
#define S_ 2048
#define H_ 1024
static constexpr float NEG_INF_F = -10000000.0f;
static constexpr float SCALE_F   = 0.03125f;   // 1/sqrt(1024)

#define BM 256
#define BN 256
#define BK 64
#define HALF_BYTES 16384     // 128 rows x 64 cols x 2B
#define OPBUF_BYTES 32768    // one operand, one K-tile (2 halves)

typedef __attribute__((ext_vector_type(4))) float  f32x4;
typedef __attribute__((ext_vector_type(8))) short  bf16x8;
typedef __attribute__((ext_vector_type(4))) short  s16x4;

__device__ __forceinline__ short f2bf(float f) {
  uint32_t u = __float_as_uint(f);
  u = (u + 0x7FFFu + ((u >> 16) & 1u)) >> 16;   // RNE bf16
  return (short)u;
}

__device__ __forceinline__ void gload16(const void* g, void* l) {
  __builtin_amdgcn_global_load_lds(
      (const __attribute__((address_space(1))) unsigned int*)g,
      (__attribute__((address_space(3))) unsigned int*)l, 16, 0, 0);
}

// Swizzled LDS fragment read: operand buffer = two 16KB halves of [128][64] bf16.
// XOR-swizzle (T2): byte ^= (row&7)<<4 — same involution as the staging source.
__device__ __forceinline__ bf16x8 lds_frag(const char* buf, int r, int k) {
  int byte = ((r >> 7) << 14) + ((r & 127) << 7) + (k << 1);
  byte ^= (r & 7) << 4;
  return *(const bf16x8*)(buf + byte);
}

// Stage one 128x64 half-tile: linear LDS dest (gload_lds requirement),
// inverse-swizzled per-lane global source (rule #21). 512 threads x 2 loads.
__device__ __forceinline__ void stage_half(const short* __restrict__ rows0,
                                           int ld, int kt, char* dst) {
  const int t = threadIdx.x, w = t >> 6, l = t & 63;
  #pragma unroll
  for (int j = 0; j < 2; ++j) {
    const int idx16 = j * 512 + w * 64 + l;       // 16B-granule index
    const int r  = idx16 >> 3;                    // row 0..127
    const int cs = ((l & 7) << 4) ^ ((r & 7) << 4);
    gload16(rows0 + (size_t)r * ld + kt + (cs >> 1),
            dst + (size_t)(j * 512 + w * 64) * 16);
  }
}

// 256x256xK bf16 GEMM core, 8 waves (2Mx4N), BK=64, double-buffered 128KB LDS.
// R8-proven schedule: all 8 loads of tile i+1 issued at tile i start; 4 MFMA
// phases (per-phase lgkmcnt(0)+sched_barrier, lockstep barriers); vmcnt(0)+
// barrier at tile end.
// MODE 0: +bias, out bf16 row-major   MODE 1: +bias, out bf16 transposed (V^T)
// MODE 2: out f32 = acc*scale + causal mask, + column (max,sumexp) partials
// MODE 3: out f32 (context, triangular K-loop + last BK tile)
template<int MODE>
__device__ __forceinline__ void gemm_core256(
    const short* __restrict__ A, const short* __restrict__ Bm,
    const float* __restrict__ bias, void* __restrict__ Cp,
    int K, int lda, int ldb, int ldc, int z, long long strC,
    int row0, int col0, int bx, char* lds, float2* __restrict__ partials) {
  char* ldsA = lds;                       // [2][OPBUF]
  char* ldsB = lds + 2 * OPBUF_BYTES;
  const int lane = threadIdx.x & 63;
  const int wid  = threadIdx.x >> 6;
  const int wm = wid >> 2;                // 0..1  (rows wm*128..+127)
  const int wn = wid & 3;                 // 0..3  (cols wn*64..+63)
  const int lr = lane & 15;
  const int lk = (lane >> 4) << 3;

  int kmain = K;
  if constexpr (MODE == 3) { int km = (bx + 1) * BM; kmain = km < K ? km : K; }
  const int ntm = kmain / BK;
  const int nt  = ntm + ((MODE == 3 && kmain < K) ? 1 : 0);  // + last-BK tile (col 2047)

  f32x4 acc[8][4] = {};

  const short* Arows0 = A + (size_t)row0 * lda;
  const short* Arows1 = Arows0 + (size_t)128 * lda;
  const short* Brows0 = Bm + (size_t)col0 * ldb;
  const short* Brows1 = Brows0 + (size_t)128 * ldb;

  auto stage_tile = [&](int buf, int kt) {          // 8 gload16 per thread
    stage_half(Brows0, ldb, kt, ldsB + buf * OPBUF_BYTES);
    stage_half(Brows1, ldb, kt, ldsB + buf * OPBUF_BYTES + HALF_BYTES);
    stage_half(Arows0, lda, kt, ldsA + buf * OPBUF_BYTES);
    stage_half(Arows1, lda, kt, ldsA + buf * OPBUF_BYTES + HALF_BYTES);
  };

  // prologue: tile 0 fully resident before phase 0
  stage_tile(0, 0);
  asm volatile("s_waitcnt vmcnt(0)" ::: "memory");
  __builtin_amdgcn_s_barrier();

  for (int i = 0; i < nt; ++i) {
    const int c = i & 1;
    const char* bA = ldsA + c * OPBUF_BYTES;
    const char* bB = ldsB + c * OPBUF_BYTES;
    if (i + 1 < nt) {                     // prefetch tile i+1 into c^1 (free now)
      const int ktn = (i + 1 < ntm) ? (i + 1) * BK : K - BK;
      stage_tile(c ^ 1, ktn);
    }

    bf16x8 bfr[4][2];
    #pragma unroll
    for (int q = 0; q < 4; ++q) {         // phase q: C-quadrant rows q*32..+31
      if (q == 0) {
        #pragma unroll
        for (int nf = 0; nf < 4; ++nf)
          #pragma unroll
          for (int ks = 0; ks < 2; ++ks)
            bfr[nf][ks] = lds_frag(bB, wn * 64 + nf * 16 + lr, ks * 32 + lk);
      }
      bf16x8 af[2][2];
      #pragma unroll
      for (int fm = 0; fm < 2; ++fm)
        #pragma unroll
        for (int ks = 0; ks < 2; ++ks)
          af[fm][ks] = lds_frag(bA, wm * 128 + q * 32 + fm * 16 + lr, ks * 32 + lk);
      asm volatile("s_waitcnt lgkmcnt(0)" ::: "memory");
      __builtin_amdgcn_sched_barrier(0);  // rule #18: pin MFMA after the wait
      __builtin_amdgcn_s_setprio(1);
      #pragma unroll
      for (int fm = 0; fm < 2; ++fm)
        #pragma unroll
        for (int nf = 0; nf < 4; ++nf)
          #pragma unroll
          for (int ks = 0; ks < 2; ++ks)
            acc[q * 2 + fm][nf] = __builtin_amdgcn_mfma_f32_16x16x32_bf16(
                af[fm][ks], bfr[nf][ks], acc[q * 2 + fm][nf], 0, 0, 0);
      __builtin_amdgcn_s_setprio(0);
      if (q < 3) __builtin_amdgcn_s_barrier();   // lockstep between phases
    }
    asm volatile("s_waitcnt vmcnt(0)" ::: "memory");
    __builtin_amdgcn_s_barrier();
  }

  float pm[4] = {-3.0e38f, -3.0e38f, -3.0e38f, -3.0e38f};

  // C/D layout per 16x16 frag: col = lane&15, row = (lane>>4)*4 + reg
  #pragma unroll
  for (int mf = 0; mf < 8; ++mf) {
    #pragma unroll
    for (int nf = 0; nf < 4; ++nf) {
      const int mb = row0 + wm * 128 + mf * 16 + ((lane >> 4) << 2);
      const int n  = col0 + wn * 64 + nf * 16 + lr;
      f32x4 a = acc[mf][nf];
      if constexpr (MODE == 0) {
        short* out = (short*)Cp;
        const float bv = bias[n];
        #pragma unroll
        for (int r = 0; r < 4; ++r)
          out[(size_t)(mb + r) * ldc + n] = f2bf(a[r] + bv);
      } else if constexpr (MODE == 1) {
        const float bv = bias[n];
        const int bb = mb >> 11;           // batch (S_=2048)
        const int ss = mb & (S_ - 1);
        s16x4 pk;
        #pragma unroll
        for (int r = 0; r < 4; ++r) pk[r] = f2bf(a[r] + bv);
        *(s16x4*)((short*)Cp + ((size_t)bb * H_ + n) * S_ + ss) = pk;
      } else if constexpr (MODE == 2) {
        float* out = (float*)Cp + (size_t)z * strC;
        #pragma unroll
        for (int r = 0; r < 4; ++r) {
          const int mrow = mb + r;
          float v = a[r] * SCALE_F + (n >= mrow ? NEG_INF_F : 0.0f);
          out[(size_t)mrow * ldc + n] = v;
          pm[nf] = fmaxf(pm[nf], v);
        }
      } else {
        float* out = (float*)Cp + (size_t)z * strC;
        #pragma unroll
        for (int r = 0; r < 4; ++r)
          out[(size_t)(mb + r) * ldc + n] = a[r];
      }
    }
  }

  if constexpr (MODE == 2) {
    // Column softmax partials over this tile's 256 rows (flash-style).
    float ps[4] = {0.0f, 0.0f, 0.0f, 0.0f};
    #pragma unroll
    for (int mf = 0; mf < 8; ++mf)
      #pragma unroll
      for (int nf = 0; nf < 4; ++nf) {
        const int mb = row0 + wm * 128 + mf * 16 + ((lane >> 4) << 2);
        const int n  = col0 + wn * 64 + nf * 16 + lr;
        f32x4 a = acc[mf][nf];
        #pragma unroll
        for (int r = 0; r < 4; ++r) {
          float v = a[r] * SCALE_F + (n >= mb + r ? NEG_INF_F : 0.0f);
          ps[nf] += __expf(v - pm[nf]);   // masked: exp(-1e7-ish) == 0 exactly
        }
      }
    float* smx = (float*)lds;             // reuse LDS (dead after K-loop)
    float* sse = smx + 512;
    #pragma unroll
    for (int nf = 0; nf < 4; ++nf) {
      float m = pm[nf], s = ps[nf];
      #pragma unroll
      for (int d = 16; d < 64; d <<= 1) { // combine lanes lr, lr+16, +32, +48
        float om = __shfl_xor(m, d);
        float os = __shfl_xor(s, d);
        float nm = fmaxf(m, om);
        s = s * __expf(m - nm) + os * __expf(om - nm);
        m = nm;
      }
      if ((lane >> 4) == 0) {
        smx[wm * 256 + wn * 64 + nf * 16 + lr] = m;
        sse[wm * 256 + wn * 64 + nf * 16 + lr] = s;
      }
    }
    __syncthreads();
    if (threadIdx.x < 256) {
      const int col = threadIdx.x;
      float m0 = smx[col], m1 = smx[256 + col];
      float s0 = sse[col], s1 = sse[256 + col];
      float mm = fmaxf(m0, m1);
      float ss = s0 * __expf(m0 - mm) + s1 * __expf(m1 - mm);
      float2 pv; pv.x = mm; pv.y = ss;
      partials[((size_t)z * 8 + (row0 >> 8)) * S_ + col0 + col] = pv;
    }
  }
}

struct ProjArgs {
  const short *xq, *xk, *xv, *wq, *wk, *wv;
  const float *bq, *bk, *bv;
  short *oq, *ok, *ov;
};

// All three projections; grid (4, 128, 3) = 1536 blocks, XCD-chunked swizzle.
__launch_bounds__(512, 1)
__global__ void proj3(ProjArgs p) {
  __shared__ char lds[4 * OPBUF_BYTES];
  const int bid = blockIdx.x + (blockIdx.y << 2) + (blockIdx.z << 9);
  const int s = (bid & 7) * 192 + (bid >> 3);       // 1536/8 = 192, bijective
  const int z = s >> 9;
  const int y = (s & 511) >> 2;
  const int x = s & 3;
  const int row0 = y * BM;
  const int col0 = x * BN;
  if (z == 0)
    gemm_core256<0>(p.xq, p.wq, p.bq, p.oq, H_, H_, H_, H_, 0, 0LL, row0, col0, x, lds, nullptr);
  else if (z == 1)
    gemm_core256<0>(p.xk, p.wk, p.bk, p.ok, H_, H_, H_, H_, 0, 0LL, row0, col0, x, lds, nullptr);
  else
    gemm_core256<1>(p.xv, p.wv, p.bv, p.ov, H_, H_, H_, 0, 0, 0LL, row0, col0, x, lds, nullptr);
}

// Scores (+scale, +causal mask, +column partials); triangular tile skip except
// last tile-column. grid (8,8,16) = 1024 blocks, XCD-chunked swizzle.
__launch_bounds__(512, 1)
__global__ void scores_k(const short* __restrict__ Qb, const short* __restrict__ Kb,
                         float* __restrict__ attn, float2* __restrict__ partials) {
  const int bid = blockIdx.x + (blockIdx.y << 3) + (blockIdx.z << 6);
  const int s = (bid & 7) * 128 + (bid >> 3);       // 1024/8 = 128, bijective
  const int bz = s >> 6;
  const int by = (s >> 3) & 7;
  const int bx = s & 7;
  if (by > bx && by != 7) return;
  __shared__ char lds[4 * OPBUF_BYTES];
  const size_t zo = (size_t)bz * S_ * H_;
  gemm_core256<2>(Qb + zo, Kb + zo, nullptr, attn, H_, H_, H_, S_, bz,
                  (long long)S_ * S_, bx * BM, by * BN, bx, lds, partials);
}

// Context = attn_b @ V^T; triangular K-loop (+ last BK tile for column 2047).
// grid (8,4,16) = 512 blocks. XCD-chunked + WORK-BALANCED mapping: within each
// XCD chunk of 64 items, dispatch rank r<32 -> bx = 7-(r>>3), r>=32 ->
// bx = (r>>3)-4, so each CU's two sequential blocks sum to exactly 37 K-tiles
// (5+32, 9+28, ...). A-panel-sharing blocks (same bz,bx; by 0..3) stay adjacent.
__launch_bounds__(512, 1)
__global__ void ctx_k(const short* __restrict__ attn_b, const short* __restrict__ Vt,
                      float* __restrict__ ctx) {
  const int bid = blockIdx.x + (blockIdx.y << 3) + (blockIdx.z << 5);
  const int chunk = bid & 7;            // XCD
  const int r = bid >> 3;               // dispatch rank within chunk, 0..63
  const int g = r >> 3;
  const int bx = (r < 32) ? (7 - g) : (g - 4);
  const int low = r & 7;
  const int by = low & 3;
  const int bz = chunk * 2 + (low >> 2);
  __shared__ char lds[4 * OPBUF_BYTES];
  gemm_core256<3>(attn_b + (size_t)bz * S_ * S_, Vt + (size_t)bz * H_ * S_,
                  nullptr, ctx, S_, S_, S_, H_, bz, (long long)S_ * H_,
                  bx * BM, by * BN, bx, lds, nullptr);
}

// All six f32->bf16 conversions in one launch. grid (2048, 4).
__launch_bounds__(256)
__global__ void cvt6(const float* __restrict__ q, const float* __restrict__ k,
                     const float* __restrict__ v, const float* __restrict__ wq,
                     const float* __restrict__ wk, const float* __restrict__ wv,
                     short* __restrict__ xq, short* __restrict__ xk,
                     short* __restrict__ xv, short* __restrict__ wqb,
                     short* __restrict__ wkb, short* __restrict__ wvb) {
  const int y = blockIdx.y;
  const int stride = gridDim.x * 256;
  if (y < 3) {
    const float* s = (y == 0) ? q : (y == 1) ? k : v;
    short* d       = (y == 0) ? xq : (y == 1) ? xk : xv;
    const int n4 = (B_ * S_ * H_) / 4;
    for (int i = blockIdx.x * 256 + threadIdx.x; i < n4; i += stride) {
      f32x4 x = ((const f32x4*)s)[i];
      s16x4 o;
      #pragma unroll
      for (int j = 0; j < 4; ++j) o[j] = f2bf(x[j]);
      ((s16x4*)d)[i] = o;
    }
  } else {
    const int w4 = (H_ * H_) / 4;          // 2^18
    for (int i = blockIdx.x * 256 + threadIdx.x; i < 3 * w4; i += stride) {
      const int wsel = i >> 18;
      const int j = i & (w4 - 1);
      const float* s = (wsel == 0) ? wq : (wsel == 1) ? wk : wv;
      short* d       = (wsel == 0) ? wqb : (wsel == 1) ? wkb : wvb;
      f32x4 x = ((const f32x4*)s)[j];
      s16x4 o;
      #pragma unroll
      for (int jj = 0; jj < 4; ++jj) o[jj] = f2bf(x[jj]);
      ((s16x4*)d)[j] = o;
    }
  }
}

// Column softmax normalize pass: combine per-tile partials (no raw re-read),
// then a single read+write pass producing f32 attn + bf16 copy.
__launch_bounds__(256)
__global__ void softmax_col(float* __restrict__ attn, short* __restrict__ attn_b,
                            const float2* __restrict__ partials) {
  const int b  = blockIdx.y;
  const int t  = threadIdx.x;
  const int cg = t & 7;
  const int qo = t >> 3;                  // 0..31
  const int k0 = blockIdx.x * 32 + cg * 4;
  float* base = attn + (size_t)b * S_ * S_;
  short* bb   = attn_b + (size_t)b * S_ * S_;
  const bool full = (k0 == S_ - 4);       // group holding the all-masked col S-1

  __shared__ f32x4 bM[8], bI[8];
  if (qo == 0) {
    const int by = k0 >> 8;
    const int bxlo = (by == 7) ? 0 : by;  // tiles scores_k actually computed
    f32x4 M4, Sm;
    #pragma unroll
    for (int i = 0; i < 4; ++i) { M4[i] = -3.0e38f; Sm[i] = 0.0f; }
    for (int bx = bxlo; bx < 8; ++bx) {
      const float2* p = partials + ((size_t)b * 8 + bx) * S_ + k0;
      #pragma unroll
      for (int i = 0; i < 4; ++i) {
        float2 pv = p[i];
        float nm = fmaxf(M4[i], pv.x);
        Sm[i] = Sm[i] * __expf(M4[i] - nm) + pv.y * __expf(pv.x - nm);
        M4[i] = nm;
      }
    }
    f32x4 inv;
    #pragma unroll
    for (int i = 0; i < 4; ++i) inv[i] = 1.0f / Sm[i];
    bM[cg] = M4;
    bI[cg] = inv;
  }
  __syncthreads();
  const f32x4 M4  = bM[cg];
  const f32x4 inv = bI[cg];

  for (int q = qo; q < S_; q += 32) {
    const size_t off = (size_t)q * S_ + k0;
    if (full || q > k0) {
      f32x4 x = *(const f32x4*)&base[off];
      f32x4 r;
      s16x4 rb;
      #pragma unroll
      for (int i = 0; i < 4; ++i) { r[i] = __expf(x[i] - M4[i]) * inv[i]; rb[i] = f2bf(r[i]); }
      *(f32x4*)&base[off] = r;
      *(s16x4*)&bb[off]   = rb;
    } else {
      f32x4 zr;
      s16x4 zb;
      #pragma unroll
      for (int i = 0; i < 4; ++i) { zr[i] = 0.0f; zb[i] = 0; }
      *(f32x4*)&base[off] = zr;
      *(s16x4*)&bb[off]   = zb;
    }
  }
}

extern "C" void kernel_launch(void* const* d_in, const int* in_sizes, int n_in,
                              void* d_out, int out_size, void* d_ws, size_t ws_size,
                              hipStream_t stream) {
  const float* queries = (const float*)d_in[0];
  const float* keys    = (const float*)d_in[1];
  const float* values  = (const float*)d_in[2];
  const float* Wq = (const float*)d_in[3];
  const float* bq = (const float*)d_in[4];
  const float* Wk = (const float*)d_in[5];
  const float* bk = (const float*)d_in[6];
  const float* Wv = (const float*)d_in[7];
  const float* bv = (const float*)d_in[8];

  float* ctx  = (float*)d_out;                       // (B,S,H) f32
  float* attn = ctx + (size_t)B_ * S_ * H_;          // (B,S,S) f32

  short* Qb = (short*)d_ws;                          // (B,S,H) bf16
  short* Kb = Qb + (size_t)B_ * S_ * H_;
  short* Vt = Kb + (size_t)B_ * S_ * H_;             // (B,H,S) bf16
  short* attn_b = Qb;                                // (B,S,S) bf16 == Qb+Kb exactly

  // bf16 weight scratch + softmax partials inside ctx region (written last):
  short* Wqb = (short*)ctx;                          // 3x (H,H) bf16 = 6 MB
  short* Wkb = Wqb + (size_t)H_ * H_;
  short* Wvb = Wkb + (size_t)H_ * H_;
  float2* partials = (float2*)(Wvb + (size_t)H_ * H_);  // (B,8,S) float2 = 2 MB
  short* Xq = (short*)attn;                          // 3x (B,S,H) bf16 in attn region
  short* Xk = Xq + (size_t)B_ * S_ * H_;
  short* Xv = Xk + (size_t)B_ * S_ * H_;

  // 0) all f32->bf16 conversions, one launch
  cvt6<<<dim3(2048, 4, 1), dim3(256, 1, 1), 0, stream>>>(queries, keys, values,
                                                         Wq, Wk, Wv,
                                                         Xq, Xk, Xv, Wqb, Wkb, Wvb);

  // 1) All projections, one launch: M = 32768, N = H, K = H
  ProjArgs pa{Xq, Xk, Xv, Wqb, Wkb, Wvb, bq, bk, bv, Qb, Kb, Vt};
  proj3<<<dim3(H_ / BN, 32768 / BM, 3), dim3(512, 1, 1), 0, stream>>>(pa);

  // 2) Scores (+scale, +causal mask, +partials) -> attn region
  scores_k<<<dim3(S_ / BM, S_ / BN, B_), dim3(512, 1, 1), 0, stream>>>(Qb, Kb, attn, partials);

  // 3) Column softmax normalize (partials-based, single pass) + bf16 copy
  softmax_col<<<dim3(S_ / 32, B_, 1), dim3(256, 1, 1), 0, stream>>>(attn, attn_b, partials);

  // 4) context = attn_b @ V^T (balanced triangular K-loop + last BK tile)
  ctx_k<<<dim3(S_ / BM, H_ / BN, B_), dim3(512, 1, 1), 0, stream>>>(attn_b, Vt, ctx);
}

// Round 12
// 798.441 us; speedup vs baseline: 1.1044x; 1.0088x over previous
//
#include <hip/hip_runtime.h>
#include <hip/hip_bf16.h>
#include <stdint.h>

#define B_ 16
#define S_ 2048
#define H_ 1024
static constexpr float NEG_INF_F = -10000000.0f;
static constexpr float SCALE_F   = 0.03125f;   // 1/sqrt(1024)

#define BM 256
#define BN 256
#define BK 64
#define HALF_BYTES 16384     // 128 rows x 64 cols x 2B
#define OPBUF_BYTES 32768    // one operand, one K-tile (2 halves)

typedef __attribute__((ext_vector_type(4))) float  f32x4;
typedef __attribute__((ext_vector_type(8))) short  bf16x8;
typedef __attribute__((ext_vector_type(4))) short  s16x4;

__device__ __forceinline__ short f2bf(float f) {
  uint32_t u = __float_as_uint(f);
  u = (u + 0x7FFFu + ((u >> 16) & 1u)) >> 16;   // RNE bf16
  return (short)u;
}

__device__ __forceinline__ void gload16(const void* g, void* l) {
  __builtin_amdgcn_global_load_lds(
      (const __attribute__((address_space(1))) unsigned int*)g,
      (__attribute__((address_space(3))) unsigned int*)l, 16, 0, 0);
}

// Swizzled LDS fragment read: operand buffer = two 16KB halves of [128][64] bf16.
// XOR-swizzle (T2): byte ^= (row&7)<<4 — same involution as the staging source.
__device__ __forceinline__ bf16x8 lds_frag(const char* buf, int r, int k) {
  int byte = ((r >> 7) << 14) + ((r & 127) << 7) + (k << 1);
  byte ^= (r & 7) << 4;
  return *(const bf16x8*)(buf + byte);
}

// Stage one 128x64 half-tile: linear LDS dest (gload_lds requirement),
// inverse-swizzled per-lane global source (rule #21). 512 threads x 2 loads.
__device__ __forceinline__ void stage_half(const short* __restrict__ rows0,
                                           int ld, int kt, char* dst) {
  const int t = threadIdx.x, w = t >> 6, l = t & 63;
  #pragma unroll
  for (int j = 0; j < 2; ++j) {
    const int idx16 = j * 512 + w * 64 + l;       // 16B-granule index
    const int r  = idx16 >> 3;                    // row 0..127
    const int cs = ((l & 7) << 4) ^ ((r & 7) << 4);
    gload16(rows0 + (size_t)r * ld + kt + (cs >> 1),
            dst + (size_t)(j * 512 + w * 64) * 16);
  }
}

// 256x256xK bf16 GEMM core, 8 waves (2Mx4N), BK=64, double-buffered 128KB LDS.
// R8-proven schedule: all 8 loads of tile i+1 issued at tile i start; 4 MFMA
// phases (per-phase lgkmcnt(0)+sched_barrier, lockstep barriers); vmcnt(0)+
// barrier at tile end.
// MODE 0: +bias, out bf16 row-major   MODE 1: +bias, out bf16 transposed (V^T)
// MODE 2: out f32 = acc*scale + causal mask, + column (max,sumexp) partials
// MODE 3: out f32 (context, triangular K-loop + last BK tile)
template<int MODE>
__device__ __forceinline__ void gemm_core256(
    const short* __restrict__ A, const short* __restrict__ Bm,
    const float* __restrict__ bias, void* __restrict__ Cp,
    int K, int lda, int ldb, int ldc, int z, long long strC,
    int row0, int col0, int bx, char* lds, float2* __restrict__ partials) {
  char* ldsA = lds;                       // [2][OPBUF]
  char* ldsB = lds + 2 * OPBUF_BYTES;
  const int lane = threadIdx.x & 63;
  const int wid  = threadIdx.x >> 6;
  const int wm = wid >> 2;                // 0..1  (rows wm*128..+127)
  const int wn = wid & 3;                 // 0..3  (cols wn*64..+63)
  const int lr = lane & 15;
  const int lk = (lane >> 4) << 3;

  int kmain = K;
  if constexpr (MODE == 3) { int km = (bx + 1) * BM; kmain = km < K ? km : K; }
  const int ntm = kmain / BK;
  const int nt  = ntm + ((MODE == 3 && kmain < K) ? 1 : 0);  // + last-BK tile (col 2047)

  f32x4 acc[8][4] = {};

  const short* Arows0 = A + (size_t)row0 * lda;
  const short* Arows1 = Arows0 + (size_t)128 * lda;
  const short* Brows0 = Bm + (size_t)col0 * ldb;
  const short* Brows1 = Brows0 + (size_t)128 * ldb;

  auto stage_tile = [&](int buf, int kt) {          // 8 gload16 per thread
    stage_half(Brows0, ldb, kt, ldsB + buf * OPBUF_BYTES);
    stage_half(Brows1, ldb, kt, ldsB + buf * OPBUF_BYTES + HALF_BYTES);
    stage_half(Arows0, lda, kt, ldsA + buf * OPBUF_BYTES);
    stage_half(Arows1, lda, kt, ldsA + buf * OPBUF_BYTES + HALF_BYTES);
  };

  // prologue: tile 0 fully resident before phase 0
  stage_tile(0, 0);
  asm volatile("s_waitcnt vmcnt(0)" ::: "memory");
  __builtin_amdgcn_s_barrier();

  for (int i = 0; i < nt; ++i) {
    const int c = i & 1;
    const char* bA = ldsA + c * OPBUF_BYTES;
    const char* bB = ldsB + c * OPBUF_BYTES;
    if (i + 1 < nt) {                     // prefetch tile i+1 into c^1 (free now)
      const int ktn = (i + 1 < ntm) ? (i + 1) * BK : K - BK;
      stage_tile(c ^ 1, ktn);
    }

    bf16x8 bfr[4][2];
    #pragma unroll
    for (int q = 0; q < 4; ++q) {         // phase q: C-quadrant rows q*32..+31
      if (q == 0) {
        #pragma unroll
        for (int nf = 0; nf < 4; ++nf)
          #pragma unroll
          for (int ks = 0; ks < 2; ++ks)
            bfr[nf][ks] = lds_frag(bB, wn * 64 + nf * 16 + lr, ks * 32 + lk);
      }
      bf16x8 af[2][2];
      #pragma unroll
      for (int fm = 0; fm < 2; ++fm)
        #pragma unroll
        for (int ks = 0; ks < 2; ++ks)
          af[fm][ks] = lds_frag(bA, wm * 128 + q * 32 + fm * 16 + lr, ks * 32 + lk);
      asm volatile("s_waitcnt lgkmcnt(0)" ::: "memory");
      __builtin_amdgcn_sched_barrier(0);  // rule #18: pin MFMA after the wait
      __builtin_amdgcn_s_setprio(1);
      #pragma unroll
      for (int fm = 0; fm < 2; ++fm)
        #pragma unroll
        for (int nf = 0; nf < 4; ++nf)
          #pragma unroll
          for (int ks = 0; ks < 2; ++ks)
            acc[q * 2 + fm][nf] = __builtin_amdgcn_mfma_f32_16x16x32_bf16(
                af[fm][ks], bfr[nf][ks], acc[q * 2 + fm][nf], 0, 0, 0);
      __builtin_amdgcn_s_setprio(0);
      if (q < 3) __builtin_amdgcn_s_barrier();   // lockstep between phases
    }
    asm volatile("s_waitcnt vmcnt(0)" ::: "memory");
    __builtin_amdgcn_s_barrier();
  }

  float pm[4] = {-3.0e38f, -3.0e38f, -3.0e38f, -3.0e38f};

  // C/D layout per 16x16 frag: col = lane&15, row = (lane>>4)*4 + reg
  #pragma unroll
  for (int mf = 0; mf < 8; ++mf) {
    #pragma unroll
    for (int nf = 0; nf < 4; ++nf) {
      const int mb = row0 + wm * 128 + mf * 16 + ((lane >> 4) << 2);
      const int n  = col0 + wn * 64 + nf * 16 + lr;
      f32x4 a = acc[mf][nf];
      if constexpr (MODE == 0) {
        short* out = (short*)Cp;
        const float bv = bias[n];
        #pragma unroll
        for (int r = 0; r < 4; ++r)
          out[(size_t)(mb + r) * ldc + n] = f2bf(a[r] + bv);
      } else if constexpr (MODE == 1) {
        const float bv = bias[n];
        const int bb = mb >> 11;           // batch (S_=2048)
        const int ss = mb & (S_ - 1);
        s16x4 pk;
        #pragma unroll
        for (int r = 0; r < 4; ++r) pk[r] = f2bf(a[r] + bv);
        *(s16x4*)((short*)Cp + ((size_t)bb * H_ + n) * S_ + ss) = pk;
      } else if constexpr (MODE == 2) {
        float* out = (float*)Cp + (size_t)z * strC;
        #pragma unroll
        for (int r = 0; r < 4; ++r) {
          const int mrow = mb + r;
          float v = a[r] * SCALE_F + (n >= mrow ? NEG_INF_F : 0.0f);
          out[(size_t)mrow * ldc + n] = v;
          pm[nf] = fmaxf(pm[nf], v);
        }
      } else {
        float* out = (float*)Cp + (size_t)z * strC;
        #pragma unroll
        for (int r = 0; r < 4; ++r)
          out[(size_t)(mb + r) * ldc + n] = a[r];
      }
    }
  }

  if constexpr (MODE == 2) {
    // Column softmax partials over this tile's 256 rows (flash-style).
    float ps[4] = {0.0f, 0.0f, 0.0f, 0.0f};
    #pragma unroll
    for (int mf = 0; mf < 8; ++mf)
      #pragma unroll
      for (int nf = 0; nf < 4; ++nf) {
        const int mb = row0 + wm * 128 + mf * 16 + ((lane >> 4) << 2);
        const int n  = col0 + wn * 64 + nf * 16 + lr;
        f32x4 a = acc[mf][nf];
        #pragma unroll
        for (int r = 0; r < 4; ++r) {
          float v = a[r] * SCALE_F + (n >= mb + r ? NEG_INF_F : 0.0f);
          ps[nf] += __expf(v - pm[nf]);   // masked: exp(-1e7-ish) == 0 exactly
        }
      }
    float* smx = (float*)lds;             // reuse LDS (dead after K-loop)
    float* sse = smx + 512;
    #pragma unroll
    for (int nf = 0; nf < 4; ++nf) {
      float m = pm[nf], s = ps[nf];
      #pragma unroll
      for (int d = 16; d < 64; d <<= 1) { // combine lanes lr, lr+16, +32, +48
        float om = __shfl_xor(m, d);
        float os = __shfl_xor(s, d);
        float nm = fmaxf(m, om);
        s = s * __expf(m - nm) + os * __expf(om - nm);
        m = nm;
      }
      if ((lane >> 4) == 0) {
        smx[wm * 256 + wn * 64 + nf * 16 + lr] = m;
        sse[wm * 256 + wn * 64 + nf * 16 + lr] = s;
      }
    }
    __syncthreads();
    if (threadIdx.x < 256) {
      const int col = threadIdx.x;
      float m0 = smx[col], m1 = smx[256 + col];
      float s0 = sse[col], s1 = sse[256 + col];
      float mm = fmaxf(m0, m1);
      float ss = s0 * __expf(m0 - mm) + s1 * __expf(m1 - mm);
      float2 pv; pv.x = mm; pv.y = ss;
      partials[((size_t)z * 8 + (row0 >> 8)) * S_ + col0 + col] = pv;
    }
  }
}

struct ProjArgs {
  const short *xq, *xk, *xv, *wq, *wk, *wv;
  const float *bq, *bk, *bv;
  short *oq, *ok, *ov;
};

// Q,K projections; grid (4, 128, 2) = 1024 blocks, XCD-chunked swizzle.
__launch_bounds__(512, 1)
__global__ void proj_qk(ProjArgs p) {
  __shared__ char lds[4 * OPBUF_BYTES];
  const int bid = blockIdx.x + (blockIdx.y << 2) + (blockIdx.z << 9);
  const int s = (bid & 7) * 128 + (bid >> 3);       // 1024/8 = 128, bijective
  const int z = s >> 9;
  const int y = (s & 511) >> 2;
  const int x = s & 3;
  if (z == 0)
    gemm_core256<0>(p.xq, p.wq, p.bq, p.oq, H_, H_, H_, H_, 0, 0LL,
                    y * BM, x * BN, x, lds, nullptr);
  else
    gemm_core256<0>(p.xk, p.wk, p.bk, p.ok, H_, H_, H_, H_, 0, 0LL,
                    y * BM, x * BN, x, lds, nullptr);
}

// V projection (transposed output); grid (4, 128) = 512 blocks, XCD swizzle.
__launch_bounds__(512, 1)
__global__ void proj_v(ProjArgs p) {
  __shared__ char lds[4 * OPBUF_BYTES];
  const int bid = blockIdx.x + (blockIdx.y << 2);
  const int s = (bid & 7) * 64 + (bid >> 3);        // 512/8 = 64, bijective
  const int y = s >> 2;
  const int x = s & 3;
  gemm_core256<1>(p.xv, p.wv, p.bv, p.ov, H_, H_, H_, 0, 0, 0LL,
                  y * BM, x * BN, x, lds, nullptr);
}

// Scores (+scale, +causal mask, +column partials); triangular tile skip except
// last tile-column. grid (8,8,16) = 1024 blocks, XCD-chunked swizzle.
__launch_bounds__(512, 1)
__global__ void scores_k(const short* __restrict__ Qb, const short* __restrict__ Kb,
                         float* __restrict__ attn, float2* __restrict__ partials) {
  const int bid = blockIdx.x + (blockIdx.y << 3) + (blockIdx.z << 6);
  const int s = (bid & 7) * 128 + (bid >> 3);       // 1024/8 = 128, bijective
  const int bz = s >> 6;
  const int by = (s >> 3) & 7;
  const int bx = s & 7;
  if (by > bx && by != 7) return;
  __shared__ char lds[4 * OPBUF_BYTES];
  const size_t zo = (size_t)bz * S_ * H_;
  gemm_core256<2>(Qb + zo, Kb + zo, nullptr, attn, H_, H_, H_, S_, bz,
                  (long long)S_ * S_, bx * BM, by * BN, bx, lds, partials);
}

// Context = attn_b @ V^T; triangular K-loop (+ last BK tile for column 2047).
// grid (8,4,16) = 512 blocks. XCD-chunked + WORK-BALANCED mapping: each CU's
// two sequential blocks sum to exactly 37 K-tiles.
__launch_bounds__(512, 1)
__global__ void ctx_k(const short* __restrict__ attn_b, const short* __restrict__ Vt,
                      float* __restrict__ ctx) {
  const int bid = blockIdx.x + (blockIdx.y << 3) + (blockIdx.z << 5);
  const int chunk = bid & 7;            // XCD
  const int r = bid >> 3;               // dispatch rank within chunk, 0..63
  const int g = r >> 3;
  const int bx = (r < 32) ? (7 - g) : (g - 4);
  const int low = r & 7;
  const int by = low & 3;
  const int bz = chunk * 2 + (low >> 2);
  __shared__ char lds[4 * OPBUF_BYTES];
  gemm_core256<3>(attn_b + (size_t)bz * S_ * S_, Vt + (size_t)bz * H_ * S_,
                  nullptr, ctx, S_, S_, S_, H_, bz, (long long)S_ * H_,
                  bx * BM, by * BN, bx, lds, nullptr);
}

// All six f32->bf16 conversions in one launch. grid (2048, 4).
__launch_bounds__(256)
__global__ void cvt6(const float* __restrict__ q, const float* __restrict__ k,
                     const float* __restrict__ v, const float* __restrict__ wq,
                     const float* __restrict__ wk, const float* __restrict__ wv,
                     short* __restrict__ xq, short* __restrict__ xk,
                     short* __restrict__ xv, short* __restrict__ wqb,
                     short* __restrict__ wkb, short* __restrict__ wvb) {
  const int y = blockIdx.y;
  const int stride = gridDim.x * 256;
  if (y < 3) {
    const float* s = (y == 0) ? q : (y == 1) ? k : v;
    short* d       = (y == 0) ? xq : (y == 1) ? xk : xv;
    const int n4 = (B_ * S_ * H_) / 4;
    for (int i = blockIdx.x * 256 + threadIdx.x; i < n4; i += stride) {
      f32x4 x = ((const f32x4*)s)[i];
      s16x4 o;
      #pragma unroll
      for (int j = 0; j < 4; ++j) o[j] = f2bf(x[j]);
      ((s16x4*)d)[i] = o;
    }
  } else {
    const int w4 = (H_ * H_) / 4;          // 2^18
    for (int i = blockIdx.x * 256 + threadIdx.x; i < 3 * w4; i += stride) {
      const int wsel = i >> 18;
      const int j = i & (w4 - 1);
      const float* s = (wsel == 0) ? wq : (wsel == 1) ? wk : wv;
      short* d       = (wsel == 0) ? wqb : (wsel == 1) ? wkb : wvb;
      f32x4 x = ((const f32x4*)s)[j];
      s16x4 o;
      #pragma unroll
      for (int jj = 0; jj < 4; ++jj) o[jj] = f2bf(x[jj]);
      ((s16x4*)d)[j] = o;
    }
  }
}

// Column softmax normalize pass: combine per-tile partials (no raw re-read),
// then a single read+write pass producing f32 attn + bf16 copy. bf16 zeros are
// written ONLY where ctx_k reads them (diagonal 256-tile or last 64 columns).
__launch_bounds__(256)
__global__ void softmax_col(float* __restrict__ attn, short* __restrict__ attn_b,
                            const float2* __restrict__ partials) {
  const int b  = blockIdx.y;
  const int t  = threadIdx.x;
  const int cg = t & 7;
  const int qo = t >> 3;                  // 0..31
  const int k0 = blockIdx.x * 32 + cg * 4;
  float* base = attn + (size_t)b * S_ * S_;
  short* bb   = attn_b + (size_t)b * S_ * S_;
  const bool full = (k0 == S_ - 4);       // group holding the all-masked col S-1

  __shared__ f32x4 bM[8], bI[8];
  if (qo == 0) {
    const int by = k0 >> 8;
    const int bxlo = (by == 7) ? 0 : by;  // tiles scores_k actually computed
    f32x4 M4, Sm;
    #pragma unroll
    for (int i = 0; i < 4; ++i) { M4[i] = -3.0e38f; Sm[i] = 0.0f; }
    for (int bx = bxlo; bx < 8; ++bx) {
      const float2* p = partials + ((size_t)b * 8 + bx) * S_ + k0;
      #pragma unroll
      for (int i = 0; i < 4; ++i) {
        float2 pv = p[i];
        float nm = fmaxf(M4[i], pv.x);
        Sm[i] = Sm[i] * __expf(M4[i] - nm) + pv.y * __expf(pv.x - nm);
        M4[i] = nm;
      }
    }
    f32x4 inv;
    #pragma unroll
    for (int i = 0; i < 4; ++i) inv[i] = 1.0f / Sm[i];
    bM[cg] = M4;
    bI[cg] = inv;
  }
  __syncthreads();
  const f32x4 M4  = bM[cg];
  const f32x4 inv = bI[cg];

  const bool zkeep = ((k0 >> 8) == 0) || (k0 >= S_ - 64);  // placeholder (per-q below)
  (void)zkeep;

  for (int q = qo; q < S_; q += 32) {
    const size_t off = (size_t)q * S_ + k0;
    if (full || q > k0) {
      f32x4 x = *(const f32x4*)&base[off];
      f32x4 r;
      s16x4 rb;
      #pragma unroll
      for (int i = 0; i < 4; ++i) { r[i] = __expf(x[i] - M4[i]) * inv[i]; rb[i] = f2bf(r[i]); }
      *(f32x4*)&base[off] = r;
      *(s16x4*)&bb[off]   = rb;
    } else {
      f32x4 zr;
      #pragma unroll
      for (int i = 0; i < 4; ++i) zr[i] = 0.0f;
      *(f32x4*)&base[off] = zr;
      // bf16 zeros only where ctx_k can read them: same 256-tile as q, or the
      // last-BK columns (k >= S-64). Elsewhere the bf16 buffer is never read.
      if (((q >> 8) == (k0 >> 8)) || (k0 >= S_ - 64)) {
        s16x4 zb;
        #pragma unroll
        for (int i = 0; i < 4; ++i) zb[i] = 0;
        *(s16x4*)&bb[off] = zb;
      }
    }
  }
}

extern "C" void kernel_launch(void* const* d_in, const int* in_sizes, int n_in,
                              void* d_out, int out_size, void* d_ws, size_t ws_size,
                              hipStream_t stream) {
  const float* queries = (const float*)d_in[0];
  const float* keys    = (const float*)d_in[1];
  const float* values  = (const float*)d_in[2];
  const float* Wq = (const float*)d_in[3];
  const float* bq = (const float*)d_in[4];
  const float* Wk = (const float*)d_in[5];
  const float* bk = (const float*)d_in[6];
  const float* Wv = (const float*)d_in[7];
  const float* bv = (const float*)d_in[8];

  float* ctx  = (float*)d_out;                       // (B,S,H) f32
  float* attn = ctx + (size_t)B_ * S_ * H_;          // (B,S,S) f32

  short* Qb = (short*)d_ws;                          // (B,S,H) bf16
  short* Kb = Qb + (size_t)B_ * S_ * H_;
  short* Vt = Kb + (size_t)B_ * S_ * H_;             // (B,H,S) bf16
  short* attn_b = Qb;                                // (B,S,S) bf16 == Qb+Kb exactly

  // bf16 weight scratch + softmax partials inside ctx region (written last):
  short* Wqb = (short*)ctx;                          // 3x (H,H) bf16 = 6 MB
  short* Wkb = Wqb + (size_t)H_ * H_;
  short* Wvb = Wkb + (size_t)H_ * H_;
  float2* partials = (float2*)(Wvb + (size_t)H_ * H_);  // (B,8,S) float2 = 2 MB
  short* Xq = (short*)attn;                          // 3x (B,S,H) bf16 in attn region
  short* Xk = Xq + (size_t)B_ * S_ * H_;
  short* Xv = Xk + (size_t)B_ * S_ * H_;

  // 0) all f32->bf16 conversions, one launch
  cvt6<<<dim3(2048, 4, 1), dim3(256, 1, 1), 0, stream>>>(queries, keys, values,
                                                         Wq, Wk, Wv,
                                                         Xq, Xk, Xv, Wqb, Wkb, Wvb);

  // 1) Projections (split Q,K / V so rocprof top-5 reveals the other kernels)
  ProjArgs pa{Xq, Xk, Xv, Wqb, Wkb, Wvb, bq, bk, bv, Qb, Kb, Vt};
  proj_qk<<<dim3(H_ / BN, 32768 / BM, 2), dim3(512, 1, 1), 0, stream>>>(pa);
  proj_v<<<dim3(H_ / BN, 32768 / BM, 1), dim3(512, 1, 1), 0, stream>>>(pa);

  // 2) Scores (+scale, +causal mask, +partials) -> attn region
  scores_k<<<dim3(S_ / BM, S_ / BN, B_), dim3(512, 1, 1), 0, stream>>>(Qb, Kb, attn, partials);

  // 3) Column softmax normalize (partials-based, single pass) + bf16 copy
  softmax_col<<<dim3(S_ / 32, B_, 1), dim3(256, 1, 1), 0, stream>>>(attn, attn_b, partials);

  // 4) context = attn_b @ V^T (balanced triangular K-loop + last BK tile)
  ctx_k<<<dim3(S_ / BM, H_ / BN, B_), dim3(512, 1, 1), 0, stream>>>(attn_b, Vt, ctx);
}